// Round 4
// baseline (83.166 us; speedup 1.0000x reference)
//
#include <hip/hip_runtime.h>

#define D_MODEL 2048
#define N_EXP 8
#define TOPK 2
#define TB 32            // tokens per block
#define PSTRIDE 72       // LDS words per token (8 chunks x 8 experts, padded 64->72)

// Block = 8 waves (512 thr). Wave w is pinned to chunk w (elements [w*256,(w+1)*256)):
// its W slice (8 experts x 64 float4-lanes) lives in registers, loaded ONCE.
// Compute phase: wave streams TB tokens; per token one coalesced float4 H load,
// 32 FMAs, 10-shuffle fold -> 8 chunk-partial logits -> LDS.
// Finish phase (after one barrier): wave w finalizes tokens 4w..4w+3 with a
// fixed-order 8-chunk sum (deterministic), 8-lane softmax + top-2 shuffles.
__global__ __launch_bounds__(512, 4) void moe_gate_kernel(
    const float* __restrict__ H, const float* __restrict__ W,
    float* __restrict__ out_idx, float* __restrict__ out_prob,
    unsigned int* __restrict__ hist_blk, int n_tokens)
{
    __shared__ float part[TB * PSTRIDE];   // 9216 B
    __shared__ unsigned int hist[N_EXP];

    const int tid = threadIdx.x;
    const int lane = tid & 63;
    const int w = tid >> 6;                // chunk id 0..7
    if (tid < N_EXP) hist[tid] = 0u;

    // W slice -> registers (once). Expert e row chunk w, this lane's float4.
    const float4* W4 = reinterpret_cast<const float4*>(W);
    float4 wv[N_EXP];
#pragma unroll
    for (int e = 0; e < N_EXP; ++e)
        wv[e] = W4[e * (D_MODEL / 4) + w * 64 + lane];

    const int t0 = blockIdx.x * TB;
    const float4* H4 = reinterpret_cast<const float4*>(H);

    // ---- compute phase ----
#pragma unroll 4
    for (int t = 0; t < TB; ++t) {
        if (t0 + t < n_tokens) {
            const float4 h = H4[(size_t)(t0 + t) * (D_MODEL / 4) + w * 64 + lane];
            float acc[N_EXP];
#pragma unroll
            for (int e = 0; e < N_EXP; ++e) {
                float a = h.x * wv[e].x;
                a = fmaf(h.y, wv[e].y, a);
                a = fmaf(h.z, wv[e].z, a);
                a = fmaf(h.w, wv[e].w, a);
                acc[e] = a;
            }
            // fold 8 -> 1 value per lane (masks 1,2,4), then complete the
            // 64-lane sum with butterflies 8,16,32.
            int c = N_EXP;
#pragma unroll
            for (int k = 0; k < 3; ++k) {
                const int m = 1 << k;
                const int half = c >> 1;
                const bool hi = (lane & m) != 0;
#pragma unroll
                for (int i = 0; i < half; ++i) {
                    float keep = hi ? acc[i + half] : acc[i];
                    float send = hi ? acc[i] : acc[i + half];
                    acc[i] = keep + __shfl_xor(send, m, 64);
                }
                c = half;
            }
            float v = acc[0];
            v += __shfl_xor(v, 8, 64);
            v += __shfl_xor(v, 16, 64);
            v += __shfl_xor(v, 32, 64);
            // lane (b0,b1,b2) holds expert e = 4*b0 + 2*b1 + b2
            if (lane < 8) {
                const int e = ((lane & 1) << 2) | (lane & 2) | ((lane >> 2) & 1);
                part[t * PSTRIDE + w * 8 + e] = v;
            }
        }
    }

    __syncthreads();

    // ---- finish phase: wave w -> tokens 4w .. 4w+3 ----
    {
        const int tl = lane >> 3;            // 0..7 (tokens duplicated x2)
        const int e = lane & 7;
        const int tloc = (w << 2) + (tl & 3);
        const int t = t0 + tloc;

        float lg = part[tloc * PSTRIDE + e];
#pragma unroll
        for (int cch = 1; cch < 8; ++cch)
            lg += part[tloc * PSTRIDE + cch * 8 + e];

        // softmax over the 8-lane expert group
        float m = lg;
        m = fmaxf(m, __shfl_xor(m, 1, 64));
        m = fmaxf(m, __shfl_xor(m, 2, 64));
        m = fmaxf(m, __shfl_xor(m, 4, 64));
        float p = expf(lg - m);
        float s = p;
        s += __shfl_xor(s, 1, 64);
        s += __shfl_xor(s, 2, 64);
        s += __shfl_xor(s, 4, 64);
        const float inv = 1.f / s;

        // top-1 (ties -> lowest index), payload (logit, idx, prob)
        float v1 = lg; int i1 = e; float p1 = p;
#pragma unroll
        for (int st = 0; st < 3; ++st) {
            const int mm = 1 << st;
            float ov = __shfl_xor(v1, mm, 64);
            int oi = __shfl_xor(i1, mm, 64);
            float op = __shfl_xor(p1, mm, 64);
            if (ov > v1 || (ov == v1 && oi < i1)) { v1 = ov; i1 = oi; p1 = op; }
        }
        // top-2
        float v2 = (e == i1) ? -INFINITY : lg;
        int i2 = e; float p2 = p;
#pragma unroll
        for (int st = 0; st < 3; ++st) {
            const int mm = 1 << st;
            float ov = __shfl_xor(v2, mm, 64);
            int oi = __shfl_xor(i2, mm, 64);
            float op = __shfl_xor(p2, mm, 64);
            if (ov > v2 || (ov == v2 && oi < i2)) { v2 = ov; i2 = oi; p2 = op; }
        }

        if (e == 0 && tl < 4 && t < n_tokens) {
            *reinterpret_cast<float2*>(&out_idx[2 * t]) = make_float2((float)i1, (float)i2);
            *reinterpret_cast<float2*>(&out_prob[2 * t]) = make_float2(p1 * inv, p2 * inv);
            atomicAdd(&hist[i1], 1u);
            atomicAdd(&hist[i2], 1u);
        }
    }

    __syncthreads();
    if (tid < N_EXP) hist_blk[blockIdx.x * N_EXP + tid] = hist[tid];
}

// 256 threads: thread (g,e) sums blocks g, g+32, ...; tree-reduce over g.
__global__ void finalize_kernel(const unsigned int* __restrict__ hist_blk, int nblk,
                                float* __restrict__ out_aux,
                                float* __restrict__ out_load, int n_tokens)
{
    __shared__ float red[256];
    const int tid = threadIdx.x;
    const int e = tid & 7, g = tid >> 3;
    unsigned int s = 0;
    for (int j = g; j < nblk; j += 32) s += hist_blk[j * N_EXP + e];
    red[tid] = (float)s;
    __syncthreads();
#pragma unroll
    for (int st = 128; st >= 8; st >>= 1) {
        if (tid < st) red[tid] += red[tid + st];
        __syncthreads();
    }
    if (tid == 0) {
        const float denom = 1.0f / (float)(n_tokens * TOPK);
        float load[N_EXP], sum = 0.f;
        for (int k = 0; k < N_EXP; ++k) { load[k] = red[k] * denom; sum += load[k]; }
        const float mean = sum / (float)N_EXP;
        float var = 0.f;
        for (int k = 0; k < N_EXP; ++k) { float d = load[k] - mean; var += d * d; }
        var /= (float)N_EXP;
        const float cv_sq = var / (mean * mean + 1e-9f);
        out_aux[0] = 0.01f * cv_sq;
        for (int k = 0; k < N_EXP; ++k) out_load[k] = load[k];
    }
}

extern "C" void kernel_launch(void* const* d_in, const int* in_sizes, int n_in,
                              void* d_out, int out_size, void* d_ws, size_t ws_size,
                              hipStream_t stream)
{
    const float* H = (const float*)d_in[0];
    const float* W = (const float*)d_in[1];
    const int n_tokens = in_sizes[0] / D_MODEL;  // 16384

    float* out = (float*)d_out;
    float* out_idx = out;
    float* out_prob = out + 2 * (size_t)n_tokens;
    float* out_aux = out + 4 * (size_t)n_tokens;
    float* out_load = out + 4 * (size_t)n_tokens + 1;

    unsigned int* hist_blk = (unsigned int*)d_ws;

    const int nblk = (n_tokens + TB - 1) / TB;  // 512
    hipLaunchKernelGGL(moe_gate_kernel, dim3(nblk), dim3(512), 0, stream,
                       H, W, out_idx, out_prob, hist_blk, n_tokens);
    hipLaunchKernelGGL(finalize_kernel, dim3(1), dim3(256), 0, stream,
                       hist_blk, nblk, out_aux, out_load, n_tokens);
}

// Round 5
// 54.802 us; speedup vs baseline: 1.5176x; 1.5176x over previous
//
#include <hip/hip_runtime.h>

#define D_MODEL 2048
#define N_EXP 8
#define TOPK 2
#define TPB 64              // tokens per block (= lanes per wave)
#define NW 8                // waves per block; wave = one k-chunk
#define KC (D_MODEL / NW)   // 256 floats per chunk
#define PSTR 68             // padded floats per token in LDS (64 -> 68, 16B-aligned)

// Lane owns ONE token; wave owns ONE 256-float k-chunk. Each lane accumulates
// 8 expert partial dots fully in-lane (no shuffles, no LDS in the hot loop).
// W addresses are wave-uniform (readfirstlane-forced) -> scalar s_load from K$.
// H: per-lane row gather (stride 8KB, 64B lines reused over 4 float4 steps).
// Tail: 2 LDS writes/lane, one barrier, wave 0 finalizes all 64 tokens in-lane.
__global__ __launch_bounds__(512, 4) void moe_gate_kernel(
    const float* __restrict__ H, const float* __restrict__ W,
    float* __restrict__ out_idx, float* __restrict__ out_prob,
    unsigned int* __restrict__ hist_blk, int n_tokens)
{
    __shared__ float part[TPB * PSTR];   // 17408 B
    __shared__ unsigned int hist[N_EXP];

    const int tid = threadIdx.x;
    const int lane = tid & 63;
    const int w = tid >> 6;              // k-chunk id 0..7
    if (tid < N_EXP) hist[tid] = 0u;

    const int t0 = blockIdx.x * TPB;
    const int t = t0 + lane;             // this lane's token

    // Wave-uniform chunk id -> scalar W base (compiler emits s_load for W).
    const int wc = __builtin_amdgcn_readfirstlane(w);
    const float4* Wu = reinterpret_cast<const float4*>(W) + wc * (KC / 4);
    const float4* Hp = reinterpret_cast<const float4*>(H) +
                       (size_t)t * (D_MODEL / 4) + wc * (KC / 4);

    float acc[N_EXP];
#pragma unroll
    for (int e = 0; e < N_EXP; ++e) acc[e] = 0.f;

    if (t < n_tokens) {
#pragma unroll 8
        for (int s = 0; s < KC / 4; ++s) {   // 64 steps: 1 load + 32 FMA each
            const float4 h = Hp[s];
#pragma unroll
            for (int e = 0; e < N_EXP; ++e) {
                const float4 wv = Wu[e * (D_MODEL / 4) + s];  // scalar (uniform)
                float a = acc[e];
                a = fmaf(h.x, wv.x, a);
                a = fmaf(h.y, wv.y, a);
                a = fmaf(h.z, wv.z, a);
                a = fmaf(h.w, wv.w, a);
                acc[e] = a;
            }
        }
        // one contiguous 32B write of the 8 partials
        float4 a0 = make_float4(acc[0], acc[1], acc[2], acc[3]);
        float4 a1 = make_float4(acc[4], acc[5], acc[6], acc[7]);
        float* dst = &part[lane * PSTR + w * 8];
        *reinterpret_cast<float4*>(dst) = a0;
        *reinterpret_cast<float4*>(dst + 4) = a1;
    }

    __syncthreads();

    // ---- finalize: wave 0, lane = token, everything in-lane ----
    if (w == 0 && t < n_tokens) {
        float lg[N_EXP];
        {
            const float* src = &part[lane * PSTR];
            float4 b0 = *reinterpret_cast<const float4*>(src);
            float4 b1 = *reinterpret_cast<const float4*>(src + 4);
            lg[0] = b0.x; lg[1] = b0.y; lg[2] = b0.z; lg[3] = b0.w;
            lg[4] = b1.x; lg[5] = b1.y; lg[6] = b1.z; lg[7] = b1.w;
#pragma unroll
            for (int c = 1; c < NW; ++c) {   // fixed order -> deterministic
                float4 c0 = *reinterpret_cast<const float4*>(src + c * 8);
                float4 c1 = *reinterpret_cast<const float4*>(src + c * 8 + 4);
                lg[0] += c0.x; lg[1] += c0.y; lg[2] += c0.z; lg[3] += c0.w;
                lg[4] += c1.x; lg[5] += c1.y; lg[6] += c1.z; lg[7] += c1.w;
            }
        }

        float m = lg[0];
#pragma unroll
        for (int e = 1; e < N_EXP; ++e) m = fmaxf(m, lg[e]);
        float p[N_EXP], s = 0.f;
#pragma unroll
        for (int e = 0; e < N_EXP; ++e) { p[e] = expf(lg[e] - m); s += p[e]; }
        const float inv = 1.f / s;

        float v1 = -INFINITY, v2 = -INFINITY;
        int i1 = 0, i2 = 0;
#pragma unroll
        for (int e = 0; e < N_EXP; ++e) {
            float vv = lg[e];
            if (vv > v1) { v2 = v1; i2 = i1; v1 = vv; i1 = e; }
            else if (vv > v2) { v2 = vv; i2 = e; }
        }

        *reinterpret_cast<float2*>(&out_idx[2 * t]) = make_float2((float)i1, (float)i2);
        *reinterpret_cast<float2*>(&out_prob[2 * t]) = make_float2(p[i1] * inv, p[i2] * inv);
        atomicAdd(&hist[i1], 1u);
        atomicAdd(&hist[i2], 1u);
    }

    __syncthreads();
    if (tid < N_EXP) hist_blk[blockIdx.x * N_EXP + tid] = hist[tid];
}

// 256 threads: thread (g,e) sums blocks g, g+32, ...; tree-reduce over g.
__global__ void finalize_kernel(const unsigned int* __restrict__ hist_blk, int nblk,
                                float* __restrict__ out_aux,
                                float* __restrict__ out_load, int n_tokens)
{
    __shared__ float red[256];
    const int tid = threadIdx.x;
    const int e = tid & 7, g = tid >> 3;
    unsigned int s = 0;
    for (int j = g; j < nblk; j += 32) s += hist_blk[j * N_EXP + e];
    red[tid] = (float)s;
    __syncthreads();
#pragma unroll
    for (int st = 128; st >= 8; st >>= 1) {
        if (tid < st) red[tid] += red[tid + st];
        __syncthreads();
    }
    if (tid == 0) {
        const float denom = 1.0f / (float)(n_tokens * TOPK);
        float load[N_EXP], sum = 0.f;
        for (int k = 0; k < N_EXP; ++k) { load[k] = red[k] * denom; sum += load[k]; }
        const float mean = sum / (float)N_EXP;
        float var = 0.f;
        for (int k = 0; k < N_EXP; ++k) { float d = load[k] - mean; var += d * d; }
        var /= (float)N_EXP;
        const float cv_sq = var / (mean * mean + 1e-9f);
        out_aux[0] = 0.01f * cv_sq;
        for (int k = 0; k < N_EXP; ++k) out_load[k] = load[k];
    }
}

extern "C" void kernel_launch(void* const* d_in, const int* in_sizes, int n_in,
                              void* d_out, int out_size, void* d_ws, size_t ws_size,
                              hipStream_t stream)
{
    const float* H = (const float*)d_in[0];
    const float* W = (const float*)d_in[1];
    const int n_tokens = in_sizes[0] / D_MODEL;  // 16384

    float* out = (float*)d_out;
    float* out_idx = out;
    float* out_prob = out + 2 * (size_t)n_tokens;
    float* out_aux = out + 4 * (size_t)n_tokens;
    float* out_load = out + 4 * (size_t)n_tokens + 1;

    unsigned int* hist_blk = (unsigned int*)d_ws;

    const int nblk = (n_tokens + TPB - 1) / TPB;  // 256
    hipLaunchKernelGGL(moe_gate_kernel, dim3(nblk), dim3(512), 0, stream,
                       H, W, out_idx, out_prob, hist_blk, n_tokens);
    hipLaunchKernelGGL(finalize_kernel, dim3(1), dim3(256), 0, stream,
                       hist_blk, nblk, out_aux, out_load, n_tokens);
}

// Round 6
// 47.328 us; speedup vs baseline: 1.7572x; 1.1579x over previous
//
#include <hip/hip_runtime.h>

#define D_MODEL 2048
#define N_EXP 8
#define TOPK 2
#define TPB 64              // tokens per block (= lanes per wave)
#define NW 16               // waves per block; wave = one k-chunk
#define KC (D_MODEL / NW)   // 128 floats per chunk
#define NSTEP (KC / 4)      // 32 float4 steps per lane
#define BATCH 8             // float4 loads in flight per batch
#define PSTR 132            // padded floats per token in LDS (16 chunks x 8, 128->132)

// Lane owns ONE token; wave owns ONE 128-float k-chunk (16 waves = full row).
// Hot loop: batched H loads (8 float4 in named regs -> 8 outstanding vmem ops)
// then 8x32 FMAs with scalar (SGPR) W operands. No shuffles, no LDS until the
// single partial write per lane. 256 blocks x 1024 thr = 4096 waves = 4/SIMD.
__global__ __launch_bounds__(1024, 4) void moe_gate_kernel(
    const float* __restrict__ H, const float* __restrict__ W,
    float* __restrict__ out_idx, float* __restrict__ out_prob,
    unsigned int* __restrict__ hist_blk, int n_tokens)
{
    __shared__ float part[TPB * PSTR];   // 33792 B
    __shared__ unsigned int hist[N_EXP];

    const int tid = threadIdx.x;
    const int lane = tid & 63;
    const int w = tid >> 6;              // k-chunk id 0..15
    if (tid < N_EXP) hist[tid] = 0u;

    const int t0 = blockIdx.x * TPB;
    const int t = t0 + lane;             // this lane's token

    // Wave-uniform chunk id -> scalar W base (s_load path).
    const int wc = __builtin_amdgcn_readfirstlane(w);
    const float4* Wu = reinterpret_cast<const float4*>(W) + wc * NSTEP;
    const float4* Hp = reinterpret_cast<const float4*>(H) +
                       (size_t)t * (D_MODEL / 4) + wc * NSTEP;

    float acc[N_EXP];
#pragma unroll
    for (int e = 0; e < N_EXP; ++e) acc[e] = 0.f;

    if (t < n_tokens) {
#pragma unroll
        for (int b = 0; b < NSTEP / BATCH; ++b) {   // 4 batches
            float4 hb[BATCH];
#pragma unroll
            for (int u = 0; u < BATCH; ++u)         // 8 loads issued back-to-back
                hb[u] = Hp[b * BATCH + u];
#pragma unroll
            for (int u = 0; u < BATCH; ++u) {
                const int s = b * BATCH + u;
#pragma unroll
                for (int e = 0; e < N_EXP; ++e) {
                    const float4 wv = Wu[e * (D_MODEL / 4) + s];  // scalar
                    float a = acc[e];
                    a = fmaf(hb[u].x, wv.x, a);
                    a = fmaf(hb[u].y, wv.y, a);
                    a = fmaf(hb[u].z, wv.z, a);
                    a = fmaf(hb[u].w, wv.w, a);
                    acc[e] = a;
                }
            }
        }
        // one contiguous 32B write of the 8 chunk-partials
        float4 a0 = make_float4(acc[0], acc[1], acc[2], acc[3]);
        float4 a1 = make_float4(acc[4], acc[5], acc[6], acc[7]);
        float* dst = &part[lane * PSTR + w * 8];
        *reinterpret_cast<float4*>(dst) = a0;
        *reinterpret_cast<float4*>(dst + 4) = a1;
    }

    __syncthreads();

    // ---- finalize: wave 0, lane = token, everything in-lane ----
    if (w == 0 && t < n_tokens) {
        float lg[N_EXP];
        {
            const float* src = &part[lane * PSTR];
            float4 b0 = *reinterpret_cast<const float4*>(src);
            float4 b1 = *reinterpret_cast<const float4*>(src + 4);
            lg[0] = b0.x; lg[1] = b0.y; lg[2] = b0.z; lg[3] = b0.w;
            lg[4] = b1.x; lg[5] = b1.y; lg[6] = b1.z; lg[7] = b1.w;
#pragma unroll
            for (int c = 1; c < NW; ++c) {   // fixed order -> deterministic
                float4 c0 = *reinterpret_cast<const float4*>(src + c * 8);
                float4 c1 = *reinterpret_cast<const float4*>(src + c * 8 + 4);
                lg[0] += c0.x; lg[1] += c0.y; lg[2] += c0.z; lg[3] += c0.w;
                lg[4] += c1.x; lg[5] += c1.y; lg[6] += c1.z; lg[7] += c1.w;
            }
        }

        float m = lg[0];
#pragma unroll
        for (int e = 1; e < N_EXP; ++e) m = fmaxf(m, lg[e]);
        float p[N_EXP], s = 0.f;
#pragma unroll
        for (int e = 0; e < N_EXP; ++e) { p[e] = expf(lg[e] - m); s += p[e]; }
        const float inv = 1.f / s;

        float v1 = -INFINITY, v2 = -INFINITY;
        int i1 = 0, i2 = 0;
#pragma unroll
        for (int e = 0; e < N_EXP; ++e) {
            float vv = lg[e];
            if (vv > v1) { v2 = v1; i2 = i1; v1 = vv; i1 = e; }
            else if (vv > v2) { v2 = vv; i2 = e; }
        }

        *reinterpret_cast<float2*>(&out_idx[2 * t]) = make_float2((float)i1, (float)i2);
        *reinterpret_cast<float2*>(&out_prob[2 * t]) = make_float2(p[i1] * inv, p[i2] * inv);
        atomicAdd(&hist[i1], 1u);
        atomicAdd(&hist[i2], 1u);
    }

    __syncthreads();
    if (tid < N_EXP) hist_blk[blockIdx.x * N_EXP + tid] = hist[tid];
}

// 256 threads: thread (g,e) sums blocks g, g+32, ...; tree-reduce over g.
__global__ void finalize_kernel(const unsigned int* __restrict__ hist_blk, int nblk,
                                float* __restrict__ out_aux,
                                float* __restrict__ out_load, int n_tokens)
{
    __shared__ float red[256];
    const int tid = threadIdx.x;
    const int e = tid & 7, g = tid >> 3;
    unsigned int s = 0;
    for (int j = g; j < nblk; j += 32) s += hist_blk[j * N_EXP + e];
    red[tid] = (float)s;
    __syncthreads();
#pragma unroll
    for (int st = 128; st >= 8; st >>= 1) {
        if (tid < st) red[tid] += red[tid + st];
        __syncthreads();
    }
    if (tid == 0) {
        const float denom = 1.0f / (float)(n_tokens * TOPK);
        float load[N_EXP], sum = 0.f;
        for (int k = 0; k < N_EXP; ++k) { load[k] = red[k] * denom; sum += load[k]; }
        const float mean = sum / (float)N_EXP;
        float var = 0.f;
        for (int k = 0; k < N_EXP; ++k) { float d = load[k] - mean; var += d * d; }
        var /= (float)N_EXP;
        const float cv_sq = var / (mean * mean + 1e-9f);
        out_aux[0] = 0.01f * cv_sq;
        for (int k = 0; k < N_EXP; ++k) out_load[k] = load[k];
    }
}

extern "C" void kernel_launch(void* const* d_in, const int* in_sizes, int n_in,
                              void* d_out, int out_size, void* d_ws, size_t ws_size,
                              hipStream_t stream)
{
    const float* H = (const float*)d_in[0];
    const float* W = (const float*)d_in[1];
    const int n_tokens = in_sizes[0] / D_MODEL;  // 16384

    float* out = (float*)d_out;
    float* out_idx = out;
    float* out_prob = out + 2 * (size_t)n_tokens;
    float* out_aux = out + 4 * (size_t)n_tokens;
    float* out_load = out + 4 * (size_t)n_tokens + 1;

    unsigned int* hist_blk = (unsigned int*)d_ws;

    const int nblk = (n_tokens + TPB - 1) / TPB;  // 256
    hipLaunchKernelGGL(moe_gate_kernel, dim3(nblk), dim3(1024), 0, stream,
                       H, W, out_idx, out_prob, hist_blk, n_tokens);
    hipLaunchKernelGGL(finalize_kernel, dim3(1), dim3(256), 0, stream,
                       hist_blk, nblk, out_aux, out_load, n_tokens);
}

// Round 7
// 44.976 us; speedup vs baseline: 1.8491x; 1.0523x over previous
//
#include <hip/hip_runtime.h>

#define D_MODEL 2048
#define NV4 (D_MODEL / 4)    // 512 float4 per row
#define N_EXP 8
#define TOPK 2
#define TPB 64               // tokens per block (= lanes)
#define NW 16                // waves per block
#define TILE 128             // floats per tile per row
#define TV4 (TILE / 4)       // 32 float4 per row-tile
#define NT (D_MODEL / TILE)  // 16 tiles
#define LSTR 129             // LDS floats per row (odd pad -> conflict-free reads)
#define PSTR 132             // floats per token in partial overlay

// Coalesced staging + in-lane compute. Per tile: all 16 waves co-stage 64 rows
// x 128 floats into LDS (wave stages 4 rows; 4x256B segments per instr), then
// wave w computes its 8-float subchunk for token=lane: 2 ds_read_b128 + 64 FMA,
// W via wave-uniform scalar loads. Double-buffered, 1 barrier/tile. No shuffles,
// no gathers. Epilogue: partials -> LDS overlay, wave 0 finalizes in-lane.
__global__ __launch_bounds__(1024, 4) void moe_gate_kernel(
    const float* __restrict__ H, const float* __restrict__ W,
    float* __restrict__ out_idx, float* __restrict__ out_prob,
    unsigned int* __restrict__ hist_blk, int n_tokens)
{
    __shared__ float lbuf[2][TPB][LSTR];   // 66048 B
    __shared__ unsigned int hist[N_EXP];

    const int tid = threadIdx.x;
    const int lane = tid & 63;
    const int w = tid >> 6;                // 0..15
    if (tid < N_EXP) hist[tid] = 0u;

    const int t0 = blockIdx.x * TPB;
    const int wc = __builtin_amdgcn_readfirstlane(w);

    // Staging coords: wave stages rows [wc*4, wc*4+4), 16 lanes per row.
    const int srow = wc * 4 + (lane >> 4);     // 0..63
    const int scol = lane & 15;                // float4 col within 16-wide group
    const bool svalid = (t0 + srow) < n_tokens;
    const float4* hrow = reinterpret_cast<const float4*>(H) + (size_t)(t0 + srow) * NV4;
    const float4 fz = make_float4(0.f, 0.f, 0.f, 0.f);

    const float4* W4 = reinterpret_cast<const float4*>(W);

    float acc[N_EXP];
#pragma unroll
    for (int e = 0; e < N_EXP; ++e) acc[e] = 0.f;

    // Prologue: stage tile 0 into buffer 0.
    {
        float4 r0 = svalid ? hrow[scol] : fz;
        float4 r1 = svalid ? hrow[scol + 16] : fz;
        *reinterpret_cast<float4*>(&lbuf[0][srow][scol * 4]) = r0;
        *reinterpret_cast<float4*>(&lbuf[0][srow][(scol + 16) * 4]) = r1;
    }
    __syncthreads();

#pragma unroll
    for (int j = 0; j < NT; ++j) {
        const int b = j & 1;
        float4 r0 = fz, r1 = fz;
        const bool pf = (j + 1 < NT);
        if (pf && svalid) {                    // issue next-tile loads early
            r0 = hrow[(j + 1) * TV4 + scol];
            r1 = hrow[(j + 1) * TV4 + scol + 16];
        }

        // Compute this wave's subchunk of tile j for token = lane.
        const float* xp = &lbuf[b][lane][wc * 8];
        const float4 x0 = *reinterpret_cast<const float4*>(xp);
        const float4 x1 = *reinterpret_cast<const float4*>(xp + 4);
#pragma unroll
        for (int e = 0; e < N_EXP; ++e) {
            const float4 w0 = W4[e * NV4 + j * TV4 + wc * 2 + 0];  // scalar
            const float4 w1 = W4[e * NV4 + j * TV4 + wc * 2 + 1];  // scalar
            float a = acc[e];
            a = fmaf(x0.x, w0.x, a);
            a = fmaf(x0.y, w0.y, a);
            a = fmaf(x0.z, w0.z, a);
            a = fmaf(x0.w, w0.w, a);
            a = fmaf(x1.x, w1.x, a);
            a = fmaf(x1.y, w1.y, a);
            a = fmaf(x1.z, w1.z, a);
            a = fmaf(x1.w, w1.w, a);
            acc[e] = a;
        }

        if (pf) {                              // write staged tile j+1
            *reinterpret_cast<float4*>(&lbuf[b ^ 1][srow][scol * 4]) = r0;
            *reinterpret_cast<float4*>(&lbuf[b ^ 1][srow][(scol + 16) * 4]) = r1;
        }
        __syncthreads();
    }

    // Partials -> LDS overlay (reuse lbuf storage; last reads are behind the
    // final barrier above). token stride 132 floats, chunk = wave.
    float* part = &lbuf[0][0][0];
    {
        float* dst = part + lane * PSTR + wc * 8;
        *reinterpret_cast<float4*>(dst) = make_float4(acc[0], acc[1], acc[2], acc[3]);
        *reinterpret_cast<float4*>(dst + 4) = make_float4(acc[4], acc[5], acc[6], acc[7]);
    }
    __syncthreads();

    // Finalize: wave 0, lane = token, all in-lane (fixed-order sum -> deterministic).
    if (w == 0 && (t0 + lane) < n_tokens) {
        const int t = t0 + lane;
        const float* src = part + lane * PSTR;
        float lg[N_EXP];
        {
            float4 b0 = *reinterpret_cast<const float4*>(src);
            float4 b1 = *reinterpret_cast<const float4*>(src + 4);
            lg[0] = b0.x; lg[1] = b0.y; lg[2] = b0.z; lg[3] = b0.w;
            lg[4] = b1.x; lg[5] = b1.y; lg[6] = b1.z; lg[7] = b1.w;
#pragma unroll
            for (int c = 1; c < NW; ++c) {
                float4 c0 = *reinterpret_cast<const float4*>(src + c * 8);
                float4 c1 = *reinterpret_cast<const float4*>(src + c * 8 + 4);
                lg[0] += c0.x; lg[1] += c0.y; lg[2] += c0.z; lg[3] += c0.w;
                lg[4] += c1.x; lg[5] += c1.y; lg[6] += c1.z; lg[7] += c1.w;
            }
        }

        float m = lg[0];
#pragma unroll
        for (int e = 1; e < N_EXP; ++e) m = fmaxf(m, lg[e]);
        float p[N_EXP], s = 0.f;
#pragma unroll
        for (int e = 0; e < N_EXP; ++e) { p[e] = expf(lg[e] - m); s += p[e]; }
        const float inv = 1.f / s;

        float v1 = -INFINITY, v2 = -INFINITY;
        int i1 = 0, i2 = 0;
#pragma unroll
        for (int e = 0; e < N_EXP; ++e) {
            float vv = lg[e];
            if (vv > v1) { v2 = v1; i2 = i1; v1 = vv; i1 = e; }
            else if (vv > v2) { v2 = vv; i2 = e; }
        }

        *reinterpret_cast<float2*>(&out_idx[2 * t]) = make_float2((float)i1, (float)i2);
        *reinterpret_cast<float2*>(&out_prob[2 * t]) = make_float2(p[i1] * inv, p[i2] * inv);
        atomicAdd(&hist[i1], 1u);
        atomicAdd(&hist[i2], 1u);
    }

    __syncthreads();
    if (tid < N_EXP) hist_blk[blockIdx.x * N_EXP + tid] = hist[tid];
}

// 256 threads: thread (g,e) sums blocks g, g+32, ...; tree-reduce over g.
__global__ void finalize_kernel(const unsigned int* __restrict__ hist_blk, int nblk,
                                float* __restrict__ out_aux,
                                float* __restrict__ out_load, int n_tokens)
{
    __shared__ float red[256];
    const int tid = threadIdx.x;
    const int e = tid & 7, g = tid >> 3;
    unsigned int s = 0;
    for (int j = g; j < nblk; j += 32) s += hist_blk[j * N_EXP + e];
    red[tid] = (float)s;
    __syncthreads();
#pragma unroll
    for (int st = 128; st >= 8; st >>= 1) {
        if (tid < st) red[tid] += red[tid + st];
        __syncthreads();
    }
    if (tid == 0) {
        const float denom = 1.0f / (float)(n_tokens * TOPK);
        float load[N_EXP], sum = 0.f;
        for (int k = 0; k < N_EXP; ++k) { load[k] = red[k] * denom; sum += load[k]; }
        const float mean = sum / (float)N_EXP;
        float var = 0.f;
        for (int k = 0; k < N_EXP; ++k) { float d = load[k] - mean; var += d * d; }
        var /= (float)N_EXP;
        const float cv_sq = var / (mean * mean + 1e-9f);
        out_aux[0] = 0.01f * cv_sq;
        for (int k = 0; k < N_EXP; ++k) out_load[k] = load[k];
    }
}

extern "C" void kernel_launch(void* const* d_in, const int* in_sizes, int n_in,
                              void* d_out, int out_size, void* d_ws, size_t ws_size,
                              hipStream_t stream)
{
    const float* H = (const float*)d_in[0];
    const float* W = (const float*)d_in[1];
    const int n_tokens = in_sizes[0] / D_MODEL;  // 16384

    float* out = (float*)d_out;
    float* out_idx = out;
    float* out_prob = out + 2 * (size_t)n_tokens;
    float* out_aux = out + 4 * (size_t)n_tokens;
    float* out_load = out + 4 * (size_t)n_tokens + 1;

    unsigned int* hist_blk = (unsigned int*)d_ws;

    const int nblk = (n_tokens + TPB - 1) / TPB;  // 256
    hipLaunchKernelGGL(moe_gate_kernel, dim3(nblk), dim3(1024), 0, stream,
                       H, W, out_idx, out_prob, hist_blk, n_tokens);
    hipLaunchKernelGGL(finalize_kernel, dim3(1), dim3(256), 0, stream,
                       hist_blk, nblk, out_aux, out_load, n_tokens);
}

// Round 8
// 43.227 us; speedup vs baseline: 1.9239x; 1.0405x over previous
//
#include <hip/hip_runtime.h>

#define D_MODEL 2048
#define NV4 (D_MODEL / 4)   // 512 float4 per row
#define N_EXP 8
#define TOPK 2
#define TPB 64              // tokens per block
#define NW 8                // waves per block
#define NT 8                // 128-float tiles per k-half (8*128 = 1024)
#define TV4 32              // float4 per row-tile
#define LSTR 129            // LDS floats per row (odd pad)
#define PSTR 68             // overlay floats per token (8 chunks x 8 exp, padded)

// Split-K: block = (64 tokens, one 1024-float k-half). 512 blocks -> 2/CU, so
// one block's barrier stalls overlap the other block's compute. Per tile:
// coalesced stage (8 lanes x float4 = 128B segments per row), transposed
// ds_read, in-lane fp32 accumulation with scalar (SGPR) W operands. Partial
// logits (8/token/half) go to ws; a second kernel finalizes tokens.
__global__ __launch_bounds__(512, 4) void gate_partial_kernel(
    const float* __restrict__ H, const float* __restrict__ W,
    float* __restrict__ part_ws, int n_tokens)
{
    __shared__ float lbuf[2][TPB][LSTR];   // 66048 B -> 2 blocks/CU

    const int tid = threadIdx.x;
    const int lane = tid & 63;
    const int w = tid >> 6;                // 0..7
    const int tb = blockIdx.x >> 1;
    const int kh = blockIdx.x & 1;         // k-half
    const int t0 = tb * TPB;
    const int wc = __builtin_amdgcn_readfirstlane(w);

    // Staging: wave stages rows [wc*8, wc*8+8); 8 lanes/row, cols scol+8i.
    const int srow = wc * 8 + (lane >> 3);
    const int scol = lane & 7;
    const bool svalid = (t0 + srow) < n_tokens;
    const float4* hrow = reinterpret_cast<const float4*>(H)
                         + (size_t)(t0 + srow) * NV4 + kh * (NV4 / 2);
    const float4* Wk = reinterpret_cast<const float4*>(W) + kh * (NV4 / 2);
    const float4 fz = make_float4(0.f, 0.f, 0.f, 0.f);

    float acc[N_EXP];
#pragma unroll
    for (int e = 0; e < N_EXP; ++e) acc[e] = 0.f;

    // Prologue: stage tile 0.
    {
        float4 r[4];
#pragma unroll
        for (int i = 0; i < 4; ++i) r[i] = svalid ? hrow[scol + 8 * i] : fz;
#pragma unroll
        for (int i = 0; i < 4; ++i)
            *reinterpret_cast<float4*>(&lbuf[0][srow][(scol + 8 * i) * 4]) = r[i];
    }
    __syncthreads();

#pragma unroll
    for (int j = 0; j < NT; ++j) {
        const int b = j & 1;
        const bool pf = (j + 1 < NT);
        float4 r[4];
#pragma unroll
        for (int i = 0; i < 4; ++i)
            r[i] = (pf && svalid) ? hrow[(j + 1) * TV4 + scol + 8 * i] : fz;

        // Compute: wave wc owns floats [wc*16, wc*16+16) of the tile; token=lane.
        const float* xp = &lbuf[b][lane][wc * 16];
        const float4 x0 = *reinterpret_cast<const float4*>(xp);
        const float4 x1 = *reinterpret_cast<const float4*>(xp + 4);
        const float4 x2 = *reinterpret_cast<const float4*>(xp + 8);
        const float4 x3 = *reinterpret_cast<const float4*>(xp + 12);
#pragma unroll
        for (int e = 0; e < N_EXP; ++e) {
            const float4 w0 = Wk[e * NV4 + j * TV4 + wc * 4 + 0];  // scalar
            const float4 w1 = Wk[e * NV4 + j * TV4 + wc * 4 + 1];
            const float4 w2 = Wk[e * NV4 + j * TV4 + wc * 4 + 2];
            const float4 w3 = Wk[e * NV4 + j * TV4 + wc * 4 + 3];
            float a = acc[e];
            a = fmaf(x0.x, w0.x, a); a = fmaf(x0.y, w0.y, a);
            a = fmaf(x0.z, w0.z, a); a = fmaf(x0.w, w0.w, a);
            a = fmaf(x1.x, w1.x, a); a = fmaf(x1.y, w1.y, a);
            a = fmaf(x1.z, w1.z, a); a = fmaf(x1.w, w1.w, a);
            a = fmaf(x2.x, w2.x, a); a = fmaf(x2.y, w2.y, a);
            a = fmaf(x2.z, w2.z, a); a = fmaf(x2.w, w2.w, a);
            a = fmaf(x3.x, w3.x, a); a = fmaf(x3.y, w3.y, a);
            a = fmaf(x3.z, w3.z, a); a = fmaf(x3.w, w3.w, a);
            acc[e] = a;
        }

        if (pf) {
#pragma unroll
            for (int i = 0; i < 4; ++i)
                *reinterpret_cast<float4*>(&lbuf[b ^ 1][srow][(scol + 8 * i) * 4]) = r[i];
        }
        __syncthreads();
    }

    // Partials -> LDS overlay (fits in lbuf[0]; last tile read lbuf[1]).
    float* part = &lbuf[0][0][0];
    {
        float* dst = part + lane * PSTR + wc * 8;
        *reinterpret_cast<float4*>(dst) = make_float4(acc[0], acc[1], acc[2], acc[3]);
        *reinterpret_cast<float4*>(dst + 4) = make_float4(acc[4], acc[5], acc[6], acc[7]);
    }
    __syncthreads();

    // Wave 0: fixed-order 8-chunk sum -> 8 partial logits -> ws.
    if (w == 0 && (t0 + lane) < n_tokens) {
        const float* src = part + lane * PSTR;
        float4 s0 = *reinterpret_cast<const float4*>(src);
        float4 s1 = *reinterpret_cast<const float4*>(src + 4);
        float lg[N_EXP] = {s0.x, s0.y, s0.z, s0.w, s1.x, s1.y, s1.z, s1.w};
#pragma unroll
        for (int c = 1; c < NW; ++c) {
            float4 c0 = *reinterpret_cast<const float4*>(src + c * 8);
            float4 c1 = *reinterpret_cast<const float4*>(src + c * 8 + 4);
            lg[0] += c0.x; lg[1] += c0.y; lg[2] += c0.z; lg[3] += c0.w;
            lg[4] += c1.x; lg[5] += c1.y; lg[6] += c1.z; lg[7] += c1.w;
        }
        float* dst = part_ws + ((size_t)(t0 + lane) * 2 + kh) * 8;
        *reinterpret_cast<float4*>(dst) = make_float4(lg[0], lg[1], lg[2], lg[3]);
        *reinterpret_cast<float4*>(dst + 4) = make_float4(lg[4], lg[5], lg[6], lg[7]);
    }
}

// One thread per token: sum the two k-half partials (fixed order), softmax,
// top-2, outputs, per-block histogram.
__global__ __launch_bounds__(512) void token_finalize_kernel(
    const float* __restrict__ part_ws,
    float* __restrict__ out_idx, float* __restrict__ out_prob,
    unsigned int* __restrict__ hist_blk, int n_tokens)
{
    __shared__ unsigned int hist[N_EXP];
    const int tid = threadIdx.x;
    if (tid < N_EXP) hist[tid] = 0u;
    __syncthreads();

    const int t = blockIdx.x * 512 + tid;
    if (t < n_tokens) {
        const float4* src = reinterpret_cast<const float4*>(part_ws + (size_t)t * 16);
        const float4 a0 = src[0], a1 = src[1], b0 = src[2], b1 = src[3];
        float lg[N_EXP] = {a0.x + b0.x, a0.y + b0.y, a0.z + b0.z, a0.w + b0.w,
                           a1.x + b1.x, a1.y + b1.y, a1.z + b1.z, a1.w + b1.w};

        float m = lg[0];
#pragma unroll
        for (int e = 1; e < N_EXP; ++e) m = fmaxf(m, lg[e]);
        float p[N_EXP], s = 0.f;
#pragma unroll
        for (int e = 0; e < N_EXP; ++e) { p[e] = expf(lg[e] - m); s += p[e]; }
        const float inv = 1.f / s;

        float v1 = -INFINITY, v2 = -INFINITY;
        int i1 = 0, i2 = 0;
#pragma unroll
        for (int e = 0; e < N_EXP; ++e) {
            float vv = lg[e];
            if (vv > v1) { v2 = v1; i2 = i1; v1 = vv; i1 = e; }
            else if (vv > v2) { v2 = vv; i2 = e; }
        }

        *reinterpret_cast<float2*>(&out_idx[2 * t]) = make_float2((float)i1, (float)i2);
        *reinterpret_cast<float2*>(&out_prob[2 * t]) = make_float2(p[i1] * inv, p[i2] * inv);
        atomicAdd(&hist[i1], 1u);
        atomicAdd(&hist[i2], 1u);
    }

    __syncthreads();
    if (tid < N_EXP) hist_blk[blockIdx.x * N_EXP + tid] = hist[tid];
}

// 256 threads: thread (g,e) sums blocks g, g+32, ...; tree-reduce over g.
__global__ void finalize_kernel(const unsigned int* __restrict__ hist_blk, int nblk,
                                float* __restrict__ out_aux,
                                float* __restrict__ out_load, int n_tokens)
{
    __shared__ float red[256];
    const int tid = threadIdx.x;
    const int e = tid & 7, g = tid >> 3;
    unsigned int s = 0;
    for (int j = g; j < nblk; j += 32) s += hist_blk[j * N_EXP + e];
    red[tid] = (float)s;
    __syncthreads();
#pragma unroll
    for (int st = 128; st >= 8; st >>= 1) {
        if (tid < st) red[tid] += red[tid + st];
        __syncthreads();
    }
    if (tid == 0) {
        const float denom = 1.0f / (float)(n_tokens * TOPK);
        float load[N_EXP], sum = 0.f;
        for (int k = 0; k < N_EXP; ++k) { load[k] = red[k] * denom; sum += load[k]; }
        const float mean = sum / (float)N_EXP;
        float var = 0.f;
        for (int k = 0; k < N_EXP; ++k) { float d = load[k] - mean; var += d * d; }
        var /= (float)N_EXP;
        const float cv_sq = var / (mean * mean + 1e-9f);
        out_aux[0] = 0.01f * cv_sq;
        for (int k = 0; k < N_EXP; ++k) out_load[k] = load[k];
    }
}

extern "C" void kernel_launch(void* const* d_in, const int* in_sizes, int n_in,
                              void* d_out, int out_size, void* d_ws, size_t ws_size,
                              hipStream_t stream)
{
    const float* H = (const float*)d_in[0];
    const float* W = (const float*)d_in[1];
    const int n_tokens = in_sizes[0] / D_MODEL;  // 16384

    float* out = (float*)d_out;
    float* out_idx = out;
    float* out_prob = out + 2 * (size_t)n_tokens;
    float* out_aux = out + 4 * (size_t)n_tokens;
    float* out_load = out + 4 * (size_t)n_tokens + 1;

    float* part_ws = (float*)d_ws;                                   // 1 MB
    unsigned int* hist_blk = (unsigned int*)((char*)d_ws + (1 << 20));

    const int nblk_t = (n_tokens + TPB - 1) / TPB;       // 256 token-blocks
    hipLaunchKernelGGL(gate_partial_kernel, dim3(nblk_t * 2), dim3(512), 0, stream,
                       H, W, part_ws, n_tokens);

    const int nblk_f = (n_tokens + 511) / 512;           // 32
    hipLaunchKernelGGL(token_finalize_kernel, dim3(nblk_f), dim3(512), 0, stream,
                       part_ws, out_idx, out_prob, hist_blk, n_tokens);

    hipLaunchKernelGGL(finalize_kernel, dim3(1), dim3(256), 0, stream,
                       hist_blk, nblk_f, out_aux, out_load, n_tokens);
}

// Round 9
// 32.926 us; speedup vs baseline: 2.5258x; 1.3128x over previous
//
#include <hip/hip_runtime.h>

#define D_MODEL 2048
#define N_EXP 8
#define TOPK 2
#define TPB 64                // tokens per block
#define SPLIT 4               // k-split factor
#define KQ (D_MODEL / SPLIT)  // 512 floats per quarter
#define TILE 64               // floats per tile per row
#define NT (KQ / TILE)        // 8 tiles
#define TSTR 65               // transposed LDS stride: [k][token], +1 pad
#define OSTR 68               // overlay floats per token (8 waves x 8 exp, padded)

// Split-K4, transposed-LDS gate. Grid = 256 token-blocks x 4 k-quarters = 1024
// blocks -> 4 blocks/CU, 8 waves/SIMD (launch_bounds(512,8) => <=64 VGPR).
// LDS tile stored TRANSPOSED [k][token] (+1 pad): staging scatter-writes and
// compute reads are both measured-class conflict-free b32 patterns. Wave w
// owns k-positions [w*8, w*8+8) of each 64-float tile; token = lane; W operands
// wave-uniform -> SGPR. Per-quarter partial logits -> part_ws[q][t][e].
__global__ __launch_bounds__(512, 8) void gate_partial_kernel(
    const float* __restrict__ H, const float* __restrict__ W,
    float* __restrict__ part_ws, int n_tokens)
{
    __shared__ float lbuf[2][TILE][TSTR];   // 33280 B -> 4 blocks/CU

    const int tid = threadIdx.x;
    const int lane = tid & 63;
    const int w = tid >> 6;               // 0..7
    const int tb = blockIdx.x >> 2;
    const int q = blockIdx.x & 3;         // k-quarter
    const int t0 = tb * TPB;
    const int wc = __builtin_amdgcn_readfirstlane(w);

    // Staging coords: thread stages row srow, float4 slots scol and scol+8.
    const int srow = tid >> 3;            // 0..63 (token row)
    const int scol = tid & 7;
    const bool svalid = (t0 + srow) < n_tokens;
    const float4* hrow = reinterpret_cast<const float4*>(H)
                         + (size_t)(t0 + srow) * (D_MODEL / 4) + q * (KQ / 4);
    const float* Wq = W + q * KQ;         // expert stride D_MODEL
    const float4 fz = make_float4(0.f, 0.f, 0.f, 0.f);

    float acc[N_EXP];
#pragma unroll
    for (int e = 0; e < N_EXP; ++e) acc[e] = 0.f;

    // Prologue: stage tile 0 (transposed scatter: 4 b32 per float4).
    {
        float4 r0 = svalid ? hrow[scol] : fz;
        float4 r1 = svalid ? hrow[scol + 8] : fz;
        const float* p0 = reinterpret_cast<const float*>(&r0);
        const float* p1 = reinterpret_cast<const float*>(&r1);
#pragma unroll
        for (int jj = 0; jj < 4; ++jj) {
            lbuf[0][4 * scol + jj][srow] = p0[jj];
            lbuf[0][4 * (scol + 8) + jj][srow] = p1[jj];
        }
    }
    __syncthreads();

#pragma unroll
    for (int j = 0; j < NT; ++j) {
        const int b = j & 1;
        const bool pf = (j + 1 < NT);
        float4 r0 = fz, r1 = fz;
        if (pf && svalid) {               // issue next-tile loads early
            r0 = hrow[(j + 1) * 16 + scol];
            r1 = hrow[(j + 1) * 16 + scol + 8];
        }

        // Compute tile j: token = lane, k = wc*8 + i (conflict-free b32 reads).
        float x[8];
#pragma unroll
        for (int i = 0; i < 8; ++i) x[i] = lbuf[b][wc * 8 + i][lane];
#pragma unroll
        for (int e = 0; e < N_EXP; ++e) {
            float a = acc[e];
#pragma unroll
            for (int i = 0; i < 8; ++i)
                a = fmaf(x[i], Wq[e * D_MODEL + j * TILE + wc * 8 + i], a);  // scalar
            acc[e] = a;
        }

        if (pf) {
            const float* p0 = reinterpret_cast<const float*>(&r0);
            const float* p1 = reinterpret_cast<const float*>(&r1);
#pragma unroll
            for (int jj = 0; jj < 4; ++jj) {
                lbuf[b ^ 1][4 * scol + jj][srow] = p0[jj];
                lbuf[b ^ 1][4 * (scol + 8) + jj][srow] = p1[jj];
            }
        }
        __syncthreads();
    }

    // Partials -> LDS overlay (overlay region is free after the last barrier).
    float* part = &lbuf[0][0][0];
    {
        float* dst = part + lane * OSTR + wc * 8;
        *reinterpret_cast<float4*>(dst) = make_float4(acc[0], acc[1], acc[2], acc[3]);
        *reinterpret_cast<float4*>(dst + 4) = make_float4(acc[4], acc[5], acc[6], acc[7]);
    }
    __syncthreads();

    // Wave 0: fixed-order 8-chunk sum -> 8 quarter-logits -> part_ws[q][t][e].
    if (w == 0 && (t0 + lane) < n_tokens) {
        const float* src = part + lane * OSTR;
        float4 s0 = *reinterpret_cast<const float4*>(src);
        float4 s1 = *reinterpret_cast<const float4*>(src + 4);
        float lg[N_EXP] = {s0.x, s0.y, s0.z, s0.w, s1.x, s1.y, s1.z, s1.w};
#pragma unroll
        for (int c = 1; c < 8; ++c) {
            float4 c0 = *reinterpret_cast<const float4*>(src + c * 8);
            float4 c1 = *reinterpret_cast<const float4*>(src + c * 8 + 4);
            lg[0] += c0.x; lg[1] += c0.y; lg[2] += c0.z; lg[3] += c0.w;
            lg[4] += c1.x; lg[5] += c1.y; lg[6] += c1.z; lg[7] += c1.w;
        }
        float* dst = part_ws + ((size_t)q * n_tokens + (t0 + lane)) * 8;
        *reinterpret_cast<float4*>(dst) = make_float4(lg[0], lg[1], lg[2], lg[3]);
        *reinterpret_cast<float4*>(dst + 4) = make_float4(lg[4], lg[5], lg[6], lg[7]);
    }
}

// One thread per token: fixed-order quarter sum, softmax, top-2, histogram.
__global__ __launch_bounds__(512) void token_finalize_kernel(
    const float* __restrict__ part_ws,
    float* __restrict__ out_idx, float* __restrict__ out_prob,
    unsigned int* __restrict__ hist_blk, int n_tokens)
{
    __shared__ unsigned int hist[N_EXP];
    const int tid = threadIdx.x;
    if (tid < N_EXP) hist[tid] = 0u;
    __syncthreads();

    const int t = blockIdx.x * 512 + tid;
    if (t < n_tokens) {
        float lg[N_EXP] = {0.f, 0.f, 0.f, 0.f, 0.f, 0.f, 0.f, 0.f};
#pragma unroll
        for (int qq = 0; qq < SPLIT; ++qq) {   // fixed order -> deterministic
            const float4* src = reinterpret_cast<const float4*>(
                part_ws + ((size_t)qq * n_tokens + t) * 8);
            const float4 a0 = src[0], a1 = src[1];
            lg[0] += a0.x; lg[1] += a0.y; lg[2] += a0.z; lg[3] += a0.w;
            lg[4] += a1.x; lg[5] += a1.y; lg[6] += a1.z; lg[7] += a1.w;
        }

        float m = lg[0];
#pragma unroll
        for (int e = 1; e < N_EXP; ++e) m = fmaxf(m, lg[e]);
        float p[N_EXP], s = 0.f;
#pragma unroll
        for (int e = 0; e < N_EXP; ++e) { p[e] = expf(lg[e] - m); s += p[e]; }
        const float inv = 1.f / s;

        float v1 = -INFINITY, v2 = -INFINITY;
        int i1 = 0, i2 = 0;
#pragma unroll
        for (int e = 0; e < N_EXP; ++e) {
            float vv = lg[e];
            if (vv > v1) { v2 = v1; i2 = i1; v1 = vv; i1 = e; }
            else if (vv > v2) { v2 = vv; i2 = e; }
        }

        *reinterpret_cast<float2*>(&out_idx[2 * t]) = make_float2((float)i1, (float)i2);
        *reinterpret_cast<float2*>(&out_prob[2 * t]) = make_float2(p[i1] * inv, p[i2] * inv);
        atomicAdd(&hist[i1], 1u);
        atomicAdd(&hist[i2], 1u);
    }

    __syncthreads();
    if (tid < N_EXP) hist_blk[blockIdx.x * N_EXP + tid] = hist[tid];
}

// 256 threads: thread (g,e) sums blocks g, g+32, ...; tree-reduce over g.
__global__ void finalize_kernel(const unsigned int* __restrict__ hist_blk, int nblk,
                                float* __restrict__ out_aux,
                                float* __restrict__ out_load, int n_tokens)
{
    __shared__ float red[256];
    const int tid = threadIdx.x;
    const int e = tid & 7, g = tid >> 3;
    unsigned int s = 0;
    for (int j = g; j < nblk; j += 32) s += hist_blk[j * N_EXP + e];
    red[tid] = (float)s;
    __syncthreads();
#pragma unroll
    for (int st = 128; st >= 8; st >>= 1) {
        if (tid < st) red[tid] += red[tid + st];
        __syncthreads();
    }
    if (tid == 0) {
        const float denom = 1.0f / (float)(n_tokens * TOPK);
        float load[N_EXP], sum = 0.f;
        for (int k = 0; k < N_EXP; ++k) { load[k] = red[k] * denom; sum += load[k]; }
        const float mean = sum / (float)N_EXP;
        float var = 0.f;
        for (int k = 0; k < N_EXP; ++k) { float d = load[k] - mean; var += d * d; }
        var /= (float)N_EXP;
        const float cv_sq = var / (mean * mean + 1e-9f);
        out_aux[0] = 0.01f * cv_sq;
        for (int k = 0; k < N_EXP; ++k) out_load[k] = load[k];
    }
}

extern "C" void kernel_launch(void* const* d_in, const int* in_sizes, int n_in,
                              void* d_out, int out_size, void* d_ws, size_t ws_size,
                              hipStream_t stream)
{
    const float* H = (const float*)d_in[0];
    const float* W = (const float*)d_in[1];
    const int n_tokens = in_sizes[0] / D_MODEL;  // 16384

    float* out = (float*)d_out;
    float* out_idx = out;
    float* out_prob = out + 2 * (size_t)n_tokens;
    float* out_aux = out + 4 * (size_t)n_tokens;
    float* out_load = out + 4 * (size_t)n_tokens + 1;

    float* part_ws = (float*)d_ws;                                   // 2 MB
    unsigned int* hist_blk = (unsigned int*)((char*)d_ws + (SPLIT * (size_t)n_tokens * 8 * 4));

    const int nblk_t = (n_tokens + TPB - 1) / TPB;       // 256 token-blocks
    hipLaunchKernelGGL(gate_partial_kernel, dim3(nblk_t * SPLIT), dim3(512), 0, stream,
                       H, W, part_ws, n_tokens);

    const int nblk_f = (n_tokens + 511) / 512;           // 32
    hipLaunchKernelGGL(token_finalize_kernel, dim3(nblk_f), dim3(512), 0, stream,
                       part_ws, out_idx, out_prob, hist_blk, n_tokens);

    hipLaunchKernelGGL(finalize_kernel, dim3(1), dim3(256), 0, stream,
                       hist_blk, nblk_f, out_aux, out_load, n_tokens);
}